// Round 12
// baseline (175.047 us; speedup 1.0000x reference)
//
#include <hip/hip_runtime.h>
#include <stdint.h>
#include <math.h>

static constexpr int NIMG  = 16;
static constexpr int HH    = 512;
static constexpr int WW    = 512;
static constexpr int TOTAL = NIMG * HH * WW;   // 4,194,304
static constexpr int WPR   = WW / 64;          // 8 qwords per row
static constexpr int QPI   = HH * WPR;         // 4096 qwords per image
static constexpr int NQ    = TOTAL / 64;       // 65,536
static constexpr int SW    = 9;                // padded LDS row stride (72B: 2-way banks, free)
static constexpr int ABLK  = 1024;             // blur/a0 blocks
static constexpr int RBLK  = 1024;             // a1 reduce blocks

// blind halo-strip thinning
static constexpr int SPI    = 4;               // strips per image
static constexpr int ORS    = HH / SPI;        // 128 owned rows per strip
static constexpr int HALO   = 16;              // halo rows each side = blind budget
static constexpr int BROWS  = ORS + 2 * HALO;  // 160 rows in LDS
static constexpr int BSUB   = 2 * HALO;        // 16 blind substeps = 8 iterations
static constexpr int BTHR   = (BROWS / 4) * WPR;  // 320 threads (4-row columns)
static constexpr int NBLIND = NIMG * SPI;      // 64 blocks
static constexpr int MAXIT2 = 120;             // fix budget: 8 + 120 = 128 total (= reference cap)

// workspace layout (bytes)
static constexpr size_t OFF_PACK  = 0;                            // u64[NQ] blurred bitmap
static constexpr size_t OFF_PACK2 = (size_t)NQ * 8;               // u64[NQ] thinned mask
static constexpr size_t OFF_A0    = OFF_PACK2 + (size_t)NQ * 8;   // double[ABLK]
static constexpr size_t OFF_A1    = OFF_A0 + (size_t)ABLK * 8;    // double[RBLK]
static constexpr size_t OFF_FLAG  = OFF_A1 + (size_t)RBLK * 8;    // int[NBLIND]

// gaussian taps exactly like numpy (f64 exp, sequential /sum, cast f32) — bit-compatible (r5-r11: absmax 0)
__device__ __forceinline__ void make_gk(float* gks) {
    if (threadIdx.x < 9) {
        double ssum = 0.0;
        for (int i = 0; i < 9; ++i) { double x = (double)(i - 4); ssum += exp(-0.5 * x * x); }
        double x = (double)((int)threadIdx.x - 4);
        gks[threadIdx.x] = (float)(exp(-0.5 * x * x) / ssum);
    }
}

// --- fused blur + threshold + pack + unmasked-loss partial. 64x64 tile per block (1024 blocks). (r11, tick removed)
__global__ void __launch_bounds__(256) blur_a0(const float* __restrict__ gt,
                                               const float4* __restrict__ pred4,
                                               uint64_t* __restrict__ packed,
                                               double* __restrict__ part_a0) {
    __shared__ float tin[72 * 72];
    __shared__ float tv[64 * 72];
    __shared__ float gks[9];
    __shared__ double sh[256];
    const int tid = threadIdx.x;
    make_gk(gks);
    const int img  = blockIdx.x >> 6;
    const int tile = blockIdx.x & 63;
    const int oy = (tile >> 3) << 6, ox = (tile & 7) << 6;
    const float* G = gt + (size_t)img * (HH * WW);
    for (int i = tid; i < 72 * 72; i += 256) {
        int r = i / 72, c = i - r * 72;
        int gy = oy - 4 + r, gx = ox - 4 + c;
        gy = gy < 0 ? -gy - 1 : (gy >= HH ? 2 * HH - 1 - gy : gy);   // symmetric pad
        gx = gx < 0 ? -gx - 1 : (gx >= WW ? 2 * WW - 1 - gx : gx);
        tin[i] = G[gy * WW + gx];
    }
    __syncthreads();
    for (int i = tid; i < 64 * 72; i += 256) {       // vertical pass first (axis=1, like ref)
        int r = i / 72, c = i - r * 72;
        float s = 0.f;
#pragma unroll
        for (int t = 0; t < 9; ++t) s += gks[t] * tin[(r + t) * 72 + c];
        tv[i] = s;
    }
    __syncthreads();
    const int lane = tid & 63, w = tid >> 6;
    for (int j = 0; j < 16; ++j) {                   // horizontal pass + threshold + pack
        int yr = w * 16 + j;
        float s = 0.f;
#pragma unroll
        for (int t = 0; t < 9; ++t) s += gks[t] * tv[yr * 72 + lane + t];
        uint64_t m = __ballot(s > 0.1f);
        if (lane == 0) packed[(size_t)img * QPI + (oy + yr) * WPR + (ox >> 6)] = m;
    }
    // --- unmasked loss partial over this 64x64 tile (gt from tin interior, pred streamed)
    double a0 = 0.0;
    for (int i = tid; i < 1024; i += 256) {          // 64 rows x 16 float4
        int r = i >> 4, c4 = i & 15;
        float4 pv = pred4[(size_t)img * (HH * WW / 4) + (size_t)(oy + r) * (WW / 4) + (ox >> 2) + c4];
        const float* gv = &tin[(r + 4) * 72 + c4 * 4 + 4];
        double d;
        d = (double)(pv.x - gv[0]); a0 += d * d;
        d = (double)(pv.y - gv[1]); a0 += d * d;
        d = (double)(pv.z - gv[2]); a0 += d * d;
        d = (double)(pv.w - gv[3]); a0 += d * d;
    }
    sh[tid] = a0;
    __syncthreads();
    for (int off = 128; off > 0; off >>= 1) {
        if (tid < off) sh[tid] += sh[tid + off];
        __syncthreads();
    }
    if (tid == 0) part_a0[blockIdx.x] = sh[0];
}

// full adder on 64 bit-lanes
__device__ __forceinline__ void fa(uint64_t a, uint64_t b, uint64_t c, uint64_t& s, uint64_t& cy) {
    uint64_t axb = a ^ b;
    s  = axb ^ c;
    cy = (a & b) | (c & axb);
}

// bit-sliced Zhang-Suen delete mask (verified exact, rounds 2-11)
__device__ __forceinline__ uint64_t zs_del(uint64_t cc, uint64_t nc, uint64_t sc, uint64_t cw, uint64_t ce,
                                           uint64_t nw, uint64_t ne, uint64_t sw, uint64_t se, int step) {
    uint64_t p2 = nc;
    uint64_t p3 = (nc >> 1) | (ne << 63);
    uint64_t p4 = (cc >> 1) | (ce << 63);
    uint64_t p5 = (sc >> 1) | (se << 63);
    uint64_t p6 = sc;
    uint64_t p7 = (sc << 1) | (sw >> 63);
    uint64_t p8 = (cc << 1) | (cw >> 63);
    uint64_t p9 = (nc << 1) | (nw >> 63);

    uint64_t s1, k1, s2, k2;
    fa(p2, p3, p4, s1, k1);
    fa(p5, p6, p7, s2, k2);
    uint64_t s3 = p8 ^ p9, k3 = p8 & p9;
    uint64_t b0, k4;
    fa(s1, s2, s3, b0, k4);
    uint64_t t1, t2;
    fa(k1, k2, k3, t1, t2);
    uint64_t b1 = t1 ^ k4;
    uint64_t k5 = t1 & k4;
    uint64_t b2 = t2 ^ k5;
    uint64_t b3 = t2 & k5;
    uint64_t condB = (b1 | b2 | b3) & ~(b3 | (b0 & b1 & b2));

    uint64_t q0 = ~p2 & p3, q1 = ~p3 & p4, q2 = ~p4 & p5, q3 = ~p5 & p6;
    uint64_t q4 = ~p6 & p7, q5 = ~p7 & p8, q6 = ~p8 & p9, q7 = ~p9 & p2;
    uint64_t u1, v1, u2, v2;
    fa(q0, q1, q2, u1, v1);
    fa(q3, q4, q5, u2, v2);
    uint64_t u3 = q6 ^ q7, v3 = q6 & q7;
    uint64_t a0, v4;
    fa(u1, u2, u3, a0, v4);
    uint64_t w1, w2;
    fa(v1, v2, v3, w1, w2);
    uint64_t a1 = w1 ^ v4;
    uint64_t ka = w1 & v4;
    uint64_t a2 = w2 ^ ka;
    uint64_t a3 = w2 & ka;
    uint64_t condA = a0 & ~a1 & ~a2 & ~a3;

    uint64_t nc1, nc2;
    if (step == 0) { nc1 = ~(p2 & p4 & p6); nc2 = ~(p4 & p6 & p8); }
    else           { nc1 = ~(p2 & p4 & p8); nc2 = ~(p2 & p6 & p8); }

    return cc & condB & condA & nc1 & nc2;
}

// --- blind halo-strip thinning: block = (img, strip). 16 substeps, NO inter-block communication.
// Validity frontier: after j substeps rows [j, BROWS-1-j] are exact -> owned rows exact at j=16.
__global__ void __launch_bounds__(BTHR) skel_blind(const uint64_t* __restrict__ gin,
                                                   uint64_t* __restrict__ gout,
                                                   int* __restrict__ flags) {
    __shared__ uint64_t SA[BROWS * SW];   // 11,520 B
    __shared__ uint64_t SB[BROWS * SW];
    __shared__ int chflag;
    const int tid = threadIdx.x;
    const int img = blockIdx.x / SPI;
    const int s   = blockIdx.x % SPI;
    const uint64_t* gi = gin + (size_t)img * QPI;
    uint64_t* go = gout + (size_t)img * QPI;
    const int gbase = s * ORS - HALO;

    for (int i = tid; i < BROWS * WPR; i += BTHR) {
        int lr = i >> 3, wx = i & 7;
        int gr = gbase + lr;
        SA[lr * SW + wx] = (gr >= 0 && gr < HH) ? gi[gr * WPR + wx] : 0;
    }
    if (tid == 0) chflag = 0;
    __syncthreads();

    const int wx = tid & 7;
    const int y0 = (tid >> 3) * 4;
    const bool xw = wx > 0, xe = wx < WPR - 1;
    uint64_t* cur = SA;
    uint64_t* nxt = SB;
    int ch = 0;

    for (int j = 1; j <= BSUB; ++j) {
        if (j == BSUB - 1) ch = 0;       // track owned-row deletions for iteration 8 (substeps 15,16)
        int b = y0 * SW + wx;
        uint64_t nwr, ncr, ner;
        if (y0 > 0) { ncr = cur[b - SW]; nwr = xw ? cur[b - SW - 1] : 0; ner = xe ? cur[b - SW + 1] : 0; }
        else        { nwr = 0; ncr = 0; ner = 0; }
        uint64_t ccr = cur[b], cwr = xw ? cur[b - 1] : 0, cer = xe ? cur[b + 1] : 0;
#pragma unroll
        for (int r = 0; r < 4; ++r) {
            int lr = y0 + r;
            uint64_t swr, scr, ser;
            if (lr < BROWS - 1) { scr = cur[b + SW]; swr = xw ? cur[b + SW - 1] : 0; ser = xe ? cur[b + SW + 1] : 0; }
            else                { swr = 0; scr = 0; ser = 0; }
            uint64_t out = ccr;          // rows 0 / BROWS-1: copy-through (outside frontier anyway)
            if (lr > 0 && lr < BROWS - 1 && ccr) {
                uint64_t del = zs_del(ccr, ncr, scr, cwr, cer, nwr, ner, swr, ser, (j - 1) & 1);
                out = ccr & ~del;
                if (del && lr >= HALO && lr < HALO + ORS) ch = 1;
            }
            nxt[b] = out;
            nwr = cwr; ncr = ccr; ner = cer;
            cwr = swr; ccr = scr; cer = ser;
            b += SW;
        }
        __syncthreads();
        uint64_t* t = cur; cur = nxt; nxt = t;
    }
    if (__any(ch) && (tid & 63) == 0) atomicOr(&chflag, 1);
    // write owned rows (exact at substep 16) to the OUTPUT buffer (no race with other blocks' loads)
    for (int i = tid; i < ORS * WPR; i += BTHR) {
        int row = i >> 3, wx2 = i & 7;
        go[(s * ORS + row) * WPR + wx2] = cur[(HALO + row) * SW + wx2];
    }
    __syncthreads();                     // chflag atomicOrs complete
    if (tid == 0) flags[blockIdx.x] = chflag;
}

// one sub-step over the full image in LDS: 4-row column walk (r8 version, proven)
__device__ __forceinline__ int zs_sub(const uint64_t* __restrict__ cur, uint64_t* __restrict__ nxt,
                                      int step, int wx, int y0, bool xw, bool xe) {
    int ch = 0;
    int b = y0 * SW + wx;
    uint64_t nwr, ncr, ner, cwr, ccr, cer;
    if (y0 > 0) {
        ncr = cur[b - SW];
        nwr = xw ? cur[b - SW - 1] : 0;
        ner = xe ? cur[b - SW + 1] : 0;
    } else { nwr = 0; ncr = 0; ner = 0; }
    ccr = cur[b];
    cwr = xw ? cur[b - 1] : 0;
    cer = xe ? cur[b + 1] : 0;
#pragma unroll
    for (int r = 0; r < 4; ++r) {
        uint64_t swr, scr, ser;
        if (y0 + r < HH - 1) {
            scr = cur[b + SW];
            swr = xw ? cur[b + SW - 1] : 0;
            ser = xe ? cur[b + SW + 1] : 0;
        } else { swr = 0; scr = 0; ser = 0; }
        uint64_t out = ccr;
        if (ccr) {
            uint64_t del = zs_del(ccr, ncr, scr, cwr, cer, nwr, ner, swr, ser, step);
            out = ccr & ~del;
            ch |= (del != 0ull);
        }
        nxt[b] = out;
        nwr = cwr; ncr = ccr; ner = cer;
        cwr = swr; ccr = scr; cer = ser;
        b += SW;
    }
    return ch;
}

// --- fix kernel: one block per image. Common case: blind converged -> immediate exit.
// Rare case: continue exact thinning from the blind output (r8 loop, 2 barriers/iter).
__global__ void __launch_bounds__(1024) skel_fix(uint64_t* __restrict__ g, const int* __restrict__ flags) {
    __shared__ int ff;
    __shared__ uint64_t SA[HH * SW];
    __shared__ uint64_t SB[HH * SW];
    __shared__ int f2[2];
    const int tid = threadIdx.x;
    const int img = blockIdx.x;
    if (tid == 0)
        ff = flags[img * SPI] | flags[img * SPI + 1] | flags[img * SPI + 2] | flags[img * SPI + 3];
    __syncthreads();
    if (ff == 0) return;                 // image converged within the blind budget (measured: typical)

    uint64_t* gimg = g + (size_t)img * QPI;
    for (int i = tid; i < QPI; i += 1024) SA[(i >> 3) * SW + (i & 7)] = gimg[i];
    if (tid == 0) { f2[0] = 0; f2[1] = 0; }
    __syncthreads();

    const int wx = tid & 7;
    const int y0 = (tid >> 3) * 4;
    const bool xw = wx > 0, xe = wx < WPR - 1;

    for (int it = 0; it < MAXIT2; ++it) {
        const int p = it & 1;
        int ch = zs_sub(SA, SB, 0, wx, y0, xw, xe);
        __syncthreads();
        ch |= zs_sub(SB, SA, 1, wx, y0, xw, xe);
        if (__any(ch) && (tid & 63) == 0) atomicOr(&f2[p], 1);
        __syncthreads();
        int stop = (f2[p] == 0);
        if (tid == 0) f2[p ^ 1] = 0;
        if (stop) break;
    }
    for (int i = tid; i < QPI; i += 1024) gimg[i] = SA[(i >> 3) * SW + (i & 7)];
}

// --- masked loss: streaming pass, per-block f64 partials, no cross-block coordination
__global__ void __launch_bounds__(256) a1_reduce(const float4* __restrict__ pred4, const float4* __restrict__ gt4,
                                                 const uint64_t* __restrict__ mask,
                                                 double* __restrict__ part_a1) {
    __shared__ double sh[256];
    const int tid = threadIdx.x;
    double a1 = 0.0;
    const int N4 = TOTAL / 4;
    for (int i = blockIdx.x * 256 + tid; i < N4; i += RBLK * 256) {
        uint64_t mq = mask[i >> 4];
        int shb = (i & 15) << 2;
        if (!((mq >> shb) & 0xFull)) continue;       // whole float4 unmasked (common): skip loads
        float4 pv = pred4[i];
        float4 gv = gt4[i];
        double d;
        if ((mq >> (shb    )) & 1) { d = (double)(pv.x - gv.x); a1 += d * d; }
        if ((mq >> (shb + 1)) & 1) { d = (double)(pv.y - gv.y); a1 += d * d; }
        if ((mq >> (shb + 2)) & 1) { d = (double)(pv.z - gv.z); a1 += d * d; }
        if ((mq >> (shb + 3)) & 1) { d = (double)(pv.w - gv.w); a1 += d * d; }
    }
    sh[tid] = a1;
    __syncthreads();
    for (int off = 128; off > 0; off >>= 1) {
        if (tid < off) sh[tid] += sh[tid + off];
        __syncthreads();
    }
    if (tid == 0) part_a1[blockIdx.x] = sh[0];
}

// --- single-block finalize: sum both partial arrays, write the loss
__global__ void __launch_bounds__(256) finalize_kernel(const double* __restrict__ part_a0,
                                                       const double* __restrict__ part_a1,
                                                       float* __restrict__ out) {
    __shared__ double sh[256];
    const int tid = threadIdx.x;
    double a = 0.0;
    for (int i = tid; i < ABLK; i += 256) a += part_a0[i];
    for (int i = tid; i < RBLK; i += 256) a += part_a1[i];
    sh[tid] = a;
    __syncthreads();
    for (int off = 128; off > 0; off >>= 1) {
        if (tid < off) sh[tid] += sh[tid + off];
        __syncthreads();
    }
    if (tid == 0) out[0] = (float)(0.5 * sh[0] / (double)TOTAL);
}

extern "C" void kernel_launch(void* const* d_in, const int* in_sizes, int n_in,
                              void* d_out, int out_size, void* d_ws, size_t ws_size,
                              hipStream_t stream) {
    const float* pred = (const float*)d_in[0];
    const float* gt   = (const float*)d_in[1];
    char* ws = (char*)d_ws;
    uint64_t* packed  = (uint64_t*)(ws + OFF_PACK);
    uint64_t* packed2 = (uint64_t*)(ws + OFF_PACK2);
    double*   part_a0 = (double*)(ws + OFF_A0);
    double*   part_a1 = (double*)(ws + OFF_A1);
    int*      flags   = (int*)(ws + OFF_FLAG);

    blur_a0<<<ABLK, 256, 0, stream>>>(gt, (const float4*)pred, packed, part_a0);
    skel_blind<<<NBLIND, BTHR, 0, stream>>>(packed, packed2, flags);
    skel_fix<<<NIMG, 1024, 0, stream>>>(packed2, flags);
    a1_reduce<<<RBLK, 256, 0, stream>>>((const float4*)pred, (const float4*)gt, packed2, part_a1);
    finalize_kernel<<<1, 256, 0, stream>>>(part_a0, part_a1, (float*)d_out);
}

// Round 13
// 124.548 us; speedup vs baseline: 1.4055x; 1.4055x over previous
//
#include <hip/hip_runtime.h>
#include <stdint.h>
#include <math.h>

static constexpr int NIMG  = 16;
static constexpr int HH    = 512;
static constexpr int WW    = 512;
static constexpr int TOTAL = NIMG * HH * WW;   // 4,194,304
static constexpr int WPR   = WW / 64;          // 8 qwords per row
static constexpr int QPI   = HH * WPR;         // 4096 qwords per image
static constexpr int NQ    = TOTAL / 64;       // 65,536
static constexpr int SW    = 9;                // padded LDS row stride (72B)

// blind halo-strip thinning (r12 concept, BSUB bug fixed, occupancy raised)
static constexpr int SPI    = 4;               // strips per image
static constexpr int ORS    = HH / SPI;        // 128 owned rows
static constexpr int HALO   = 16;              // halo rows each side
static constexpr int BROWS  = ORS + 2 * HALO;  // 160 rows in LDS
static constexpr int BSUB   = HALO;            // 16 blind substeps = 8 iters (frontier-exact: [16,143])
static constexpr int BTHR   = (BROWS / 2) * WPR;  // 640 threads (2-row cells) = 10 waves
static constexpr int NBLIND = NIMG * SPI;      // 64 strip blocks
static constexpr int A0BLK  = 192;             // a0 blocks riding in the same dispatch
static constexpr int MAXIT2 = 120;             // fix budget: 8 + 120 = 128 (= reference cap)
static constexpr int RBLK   = 1024;            // a1 reduce blocks

// workspace layout (bytes)
static constexpr size_t OFF_PACK  = 0;                            // u64[NQ] blurred bitmap
static constexpr size_t OFF_PACK2 = (size_t)NQ * 8;               // u64[NQ] thinned mask
static constexpr size_t OFF_A0    = OFF_PACK2 + (size_t)NQ * 8;   // double[A0BLK]
static constexpr size_t OFF_A1    = OFF_A0 + (size_t)A0BLK * 8;   // double[RBLK]
static constexpr size_t OFF_FLAG  = OFF_A1 + (size_t)RBLK * 8;    // int[NBLIND]

// gaussian taps exactly like numpy (f64 exp, sequential /sum, cast f32) — bit-compatible (r5-r12: absmax 0)
__device__ __forceinline__ void make_gk(float* gks) {
    if (threadIdx.x < 9) {
        double ssum = 0.0;
        for (int i = 0; i < 9; ++i) { double x = (double)(i - 4); ssum += exp(-0.5 * x * x); }
        double x = (double)((int)threadIdx.x - 4);
        gks[threadIdx.x] = (float)(exp(-0.5 * x * x) / ssum);
    }
}

// --- fused separable blur + threshold + bit-pack. 64x64 tile per block (r6-proven, lean).
__global__ void __launch_bounds__(256) fused_blur(const float* __restrict__ gt,
                                                  uint64_t* __restrict__ packed) {
    __shared__ float tin[72 * 72];
    __shared__ float tv[64 * 72];
    __shared__ float gks[9];
    const int tid = threadIdx.x;
    make_gk(gks);
    const int img  = blockIdx.x >> 6;
    const int tile = blockIdx.x & 63;
    const int oy = (tile >> 3) << 6, ox = (tile & 7) << 6;
    const float* G = gt + (size_t)img * (HH * WW);
    for (int i = tid; i < 72 * 72; i += 256) {
        int r = i / 72, c = i - r * 72;
        int gy = oy - 4 + r, gx = ox - 4 + c;
        gy = gy < 0 ? -gy - 1 : (gy >= HH ? 2 * HH - 1 - gy : gy);   // symmetric pad
        gx = gx < 0 ? -gx - 1 : (gx >= WW ? 2 * WW - 1 - gx : gx);
        tin[i] = G[gy * WW + gx];
    }
    __syncthreads();
    for (int i = tid; i < 64 * 72; i += 256) {       // vertical pass first (axis=1, like ref)
        int r = i / 72, c = i - r * 72;
        float s = 0.f;
#pragma unroll
        for (int t = 0; t < 9; ++t) s += gks[t] * tin[(r + t) * 72 + c];
        tv[i] = s;
    }
    __syncthreads();
    const int lane = tid & 63, w = tid >> 6;
    for (int j = 0; j < 16; ++j) {                   // horizontal pass + threshold + pack
        int yr = w * 16 + j;
        float s = 0.f;
#pragma unroll
        for (int t = 0; t < 9; ++t) s += gks[t] * tv[yr * 72 + lane + t];
        uint64_t m = __ballot(s > 0.1f);
        if (lane == 0) packed[(size_t)img * QPI + (oy + yr) * WPR + (ox >> 6)] = m;
    }
}

// full adder on 64 bit-lanes
__device__ __forceinline__ void fa(uint64_t a, uint64_t b, uint64_t c, uint64_t& s, uint64_t& cy) {
    uint64_t axb = a ^ b;
    s  = axb ^ c;
    cy = (a & b) | (c & axb);
}

// bit-sliced Zhang-Suen delete mask (verified exact, rounds 2-12)
__device__ __forceinline__ uint64_t zs_del(uint64_t cc, uint64_t nc, uint64_t sc, uint64_t cw, uint64_t ce,
                                           uint64_t nw, uint64_t ne, uint64_t sw, uint64_t se, int step) {
    uint64_t p2 = nc;
    uint64_t p3 = (nc >> 1) | (ne << 63);
    uint64_t p4 = (cc >> 1) | (ce << 63);
    uint64_t p5 = (sc >> 1) | (se << 63);
    uint64_t p6 = sc;
    uint64_t p7 = (sc << 1) | (sw >> 63);
    uint64_t p8 = (cc << 1) | (cw >> 63);
    uint64_t p9 = (nc << 1) | (nw >> 63);

    uint64_t s1, k1, s2, k2;
    fa(p2, p3, p4, s1, k1);
    fa(p5, p6, p7, s2, k2);
    uint64_t s3 = p8 ^ p9, k3 = p8 & p9;
    uint64_t b0, k4;
    fa(s1, s2, s3, b0, k4);
    uint64_t t1, t2;
    fa(k1, k2, k3, t1, t2);
    uint64_t b1 = t1 ^ k4;
    uint64_t k5 = t1 & k4;
    uint64_t b2 = t2 ^ k5;
    uint64_t b3 = t2 & k5;
    uint64_t condB = (b1 | b2 | b3) & ~(b3 | (b0 & b1 & b2));

    uint64_t q0 = ~p2 & p3, q1 = ~p3 & p4, q2 = ~p4 & p5, q3 = ~p5 & p6;
    uint64_t q4 = ~p6 & p7, q5 = ~p7 & p8, q6 = ~p8 & p9, q7 = ~p9 & p2;
    uint64_t u1, v1, u2, v2;
    fa(q0, q1, q2, u1, v1);
    fa(q3, q4, q5, u2, v2);
    uint64_t u3 = q6 ^ q7, v3 = q6 & q7;
    uint64_t a0, v4;
    fa(u1, u2, u3, a0, v4);
    uint64_t w1, w2;
    fa(v1, v2, v3, w1, w2);
    uint64_t a1 = w1 ^ v4;
    uint64_t ka = w1 & v4;
    uint64_t a2 = w2 ^ ka;
    uint64_t a3 = w2 & ka;
    uint64_t condA = a0 & ~a1 & ~a2 & ~a3;

    uint64_t nc1, nc2;
    if (step == 0) { nc1 = ~(p2 & p4 & p6); nc2 = ~(p4 & p6 & p8); }
    else           { nc1 = ~(p2 & p4 & p8); nc2 = ~(p2 & p6 & p8); }

    return cc & condB & condA & nc1 & nc2;
}

// --- mega2: blocks [0,64) = blind halo-strip thinning (16 substeps, no inter-block comms);
//            blocks [64,256) = unmasked-loss (a0) streaming reduction, hidden under the thinning.
__global__ void __launch_bounds__(BTHR) mega2(const uint64_t* __restrict__ gin,
                                              uint64_t* __restrict__ gout,
                                              int* __restrict__ flags,
                                              const float4* __restrict__ pred4,
                                              const float4* __restrict__ gt4,
                                              double* __restrict__ part_a0) {
    const int tid = threadIdx.x;
    if (blockIdx.x < NBLIND) {
        __shared__ uint64_t SA[BROWS * SW];   // 11,520 B
        __shared__ uint64_t SB[BROWS * SW];
        __shared__ int chflag;
        const int img = blockIdx.x >> 2;
        const int s   = blockIdx.x & 3;
        const uint64_t* gi = gin + (size_t)img * QPI;
        uint64_t* go = gout + (size_t)img * QPI;
        const int gbase = s * ORS - HALO;

        for (int i = tid; i < BROWS * WPR; i += BTHR) {
            int lr = i >> 3, wx = i & 7;
            int gr = gbase + lr;
            SA[lr * SW + wx] = (gr >= 0 && gr < HH) ? gi[gr * WPR + wx] : 0;
        }
        if (tid == 0) chflag = 0;
        __syncthreads();

        const int wx = tid & 7;
        const int y0 = (tid >> 3) * 2;           // 2-row cell
        const bool xw = wx > 0, xe = wx < WPR - 1;
        uint64_t* cur = SA;
        uint64_t* nxt = SB;
        int ch = 0;

        for (int j = 1; j <= BSUB; ++j) {
            if (j == BSUB - 1) ch = 0;           // certify iteration 8 (substeps 15,16), owned rows
            int b = y0 * SW + wx;
            uint64_t nwr, ncr, ner;
            if (y0 > 0) { ncr = cur[b - SW]; nwr = xw ? cur[b - SW - 1] : 0; ner = xe ? cur[b - SW + 1] : 0; }
            else        { nwr = 0; ncr = 0; ner = 0; }
            uint64_t ccr = cur[b], cwr = xw ? cur[b - 1] : 0, cer = xe ? cur[b + 1] : 0;
#pragma unroll
            for (int r = 0; r < 2; ++r) {
                int lr = y0 + r;
                uint64_t swr, scr, ser;
                if (lr < BROWS - 1) { scr = cur[b + SW]; swr = xw ? cur[b + SW - 1] : 0; ser = xe ? cur[b + SW + 1] : 0; }
                else                { swr = 0; scr = 0; ser = 0; }
                uint64_t out = ccr;              // rows 0/159 copy-through (outside frontier)
                if (lr > 0 && lr < BROWS - 1 && ccr) {
                    uint64_t del = zs_del(ccr, ncr, scr, cwr, cer, nwr, ner, swr, ser, (j - 1) & 1);
                    out = ccr & ~del;
                    if (del && lr >= HALO && lr < HALO + ORS) ch = 1;
                }
                nxt[b] = out;
                nwr = cwr; ncr = ccr; ner = cer;
                cwr = swr; ccr = scr; cer = ser;
                b += SW;
            }
            __syncthreads();
            uint64_t* t = cur; cur = nxt; nxt = t;
        }
        if (__any(ch) && (tid & 63) == 0) atomicOr(&chflag, 1);
        for (int i = tid; i < ORS * WPR; i += BTHR) {      // owned rows exact at substep 16
            int row = i >> 3, wx2 = i & 7;
            go[(s * ORS + row) * WPR + wx2] = cur[(HALO + row) * SW + wx2];
        }
        __syncthreads();
        if (tid == 0) flags[blockIdx.x] = chflag;
    } else {
        // --- a0 = sum(diff^2), no mask dependence: runs concurrently with the thinning blocks
        __shared__ double sh[1024];
        double a0 = 0.0;
        const int N4 = TOTAL / 4;
        for (int i = (blockIdx.x - NBLIND) * BTHR + tid; i < N4; i += A0BLK * BTHR) {
            float4 pv = pred4[i];
            float4 gv = gt4[i];
            double d;
            d = (double)(pv.x - gv.x); a0 += d * d;
            d = (double)(pv.y - gv.y); a0 += d * d;
            d = (double)(pv.z - gv.z); a0 += d * d;
            d = (double)(pv.w - gv.w); a0 += d * d;
        }
        sh[tid] = a0;
        if (tid < 1024 - BTHR) sh[BTHR + tid] = 0.0;
        __syncthreads();
        for (int off = 512; off > 0; off >>= 1) {
            if (tid < off) sh[tid] += sh[tid + off];
            __syncthreads();
        }
        if (tid == 0) part_a0[blockIdx.x - NBLIND] = sh[0];
    }
}

// one sub-step over the full image in LDS: 4-row column walk (r8 version, proven)
__device__ __forceinline__ int zs_sub(const uint64_t* __restrict__ cur, uint64_t* __restrict__ nxt,
                                      int step, int wx, int y0, bool xw, bool xe) {
    int ch = 0;
    int b = y0 * SW + wx;
    uint64_t nwr, ncr, ner, cwr, ccr, cer;
    if (y0 > 0) {
        ncr = cur[b - SW];
        nwr = xw ? cur[b - SW - 1] : 0;
        ner = xe ? cur[b - SW + 1] : 0;
    } else { nwr = 0; ncr = 0; ner = 0; }
    ccr = cur[b];
    cwr = xw ? cur[b - 1] : 0;
    cer = xe ? cur[b + 1] : 0;
#pragma unroll
    for (int r = 0; r < 4; ++r) {
        uint64_t swr, scr, ser;
        if (y0 + r < HH - 1) {
            scr = cur[b + SW];
            swr = xw ? cur[b + SW - 1] : 0;
            ser = xe ? cur[b + SW + 1] : 0;
        } else { swr = 0; scr = 0; ser = 0; }
        uint64_t out = ccr;
        if (ccr) {
            uint64_t del = zs_del(ccr, ncr, scr, cwr, cer, nwr, ner, swr, ser, step);
            out = ccr & ~del;
            ch |= (del != 0ull);
        }
        nxt[b] = out;
        nwr = cwr; ncr = ccr; ner = cer;
        cwr = swr; ccr = scr; cer = ser;
        b += SW;
    }
    return ch;
}

// --- fix kernel: one block per image. Blind-converged (typical) -> immediate exit; else exact continuation.
__global__ void __launch_bounds__(1024) skel_fix(uint64_t* __restrict__ g, const int* __restrict__ flags) {
    __shared__ int ff;
    __shared__ uint64_t SA[HH * SW];
    __shared__ uint64_t SB[HH * SW];
    __shared__ int f2[2];
    const int tid = threadIdx.x;
    const int img = blockIdx.x;
    if (tid == 0)
        ff = flags[img * SPI] | flags[img * SPI + 1] | flags[img * SPI + 2] | flags[img * SPI + 3];
    __syncthreads();
    if (ff == 0) return;

    uint64_t* gimg = g + (size_t)img * QPI;
    for (int i = tid; i < QPI; i += 1024) SA[(i >> 3) * SW + (i & 7)] = gimg[i];
    if (tid == 0) { f2[0] = 0; f2[1] = 0; }
    __syncthreads();

    const int wx = tid & 7;
    const int y0 = (tid >> 3) * 4;
    const bool xw = wx > 0, xe = wx < WPR - 1;

    for (int it = 0; it < MAXIT2; ++it) {
        const int p = it & 1;
        int ch = zs_sub(SA, SB, 0, wx, y0, xw, xe);
        __syncthreads();
        ch |= zs_sub(SB, SA, 1, wx, y0, xw, xe);
        if (__any(ch) && (tid & 63) == 0) atomicOr(&f2[p], 1);
        __syncthreads();
        int stop = (f2[p] == 0);
        if (tid == 0) f2[p ^ 1] = 0;
        if (stop) break;
    }
    for (int i = tid; i < QPI; i += 1024) gimg[i] = SA[(i >> 3) * SW + (i & 7)];
}

// --- masked loss: streaming pass with all-zero-nibble load skip; per-block f64 partials
__global__ void __launch_bounds__(256) a1_reduce(const float4* __restrict__ pred4, const float4* __restrict__ gt4,
                                                 const uint64_t* __restrict__ mask,
                                                 double* __restrict__ part_a1) {
    __shared__ double sh[256];
    const int tid = threadIdx.x;
    double a1 = 0.0;
    const int N4 = TOTAL / 4;
    for (int i = blockIdx.x * 256 + tid; i < N4; i += RBLK * 256) {
        uint64_t mq = mask[i >> 4];
        int shb = (i & 15) << 2;
        if (!((mq >> shb) & 0xFull)) continue;
        float4 pv = pred4[i];
        float4 gv = gt4[i];
        double d;
        if ((mq >> (shb    )) & 1) { d = (double)(pv.x - gv.x); a1 += d * d; }
        if ((mq >> (shb + 1)) & 1) { d = (double)(pv.y - gv.y); a1 += d * d; }
        if ((mq >> (shb + 2)) & 1) { d = (double)(pv.z - gv.z); a1 += d * d; }
        if ((mq >> (shb + 3)) & 1) { d = (double)(pv.w - gv.w); a1 += d * d; }
    }
    sh[tid] = a1;
    __syncthreads();
    for (int off = 128; off > 0; off >>= 1) {
        if (tid < off) sh[tid] += sh[tid + off];
        __syncthreads();
    }
    if (tid == 0) part_a1[blockIdx.x] = sh[0];
}

// --- single-block finalize
__global__ void __launch_bounds__(256) finalize_kernel(const double* __restrict__ part_a0,
                                                       const double* __restrict__ part_a1,
                                                       float* __restrict__ out) {
    __shared__ double sh[256];
    const int tid = threadIdx.x;
    double a = 0.0;
    for (int i = tid; i < A0BLK; i += 256) a += part_a0[i];
    for (int i = tid; i < RBLK; i += 256) a += part_a1[i];
    sh[tid] = a;
    __syncthreads();
    for (int off = 128; off > 0; off >>= 1) {
        if (tid < off) sh[tid] += sh[tid + off];
        __syncthreads();
    }
    if (tid == 0) out[0] = (float)(0.5 * sh[0] / (double)TOTAL);
}

extern "C" void kernel_launch(void* const* d_in, const int* in_sizes, int n_in,
                              void* d_out, int out_size, void* d_ws, size_t ws_size,
                              hipStream_t stream) {
    const float* pred = (const float*)d_in[0];
    const float* gt   = (const float*)d_in[1];
    char* ws = (char*)d_ws;
    uint64_t* packed  = (uint64_t*)(ws + OFF_PACK);
    uint64_t* packed2 = (uint64_t*)(ws + OFF_PACK2);
    double*   part_a0 = (double*)(ws + OFF_A0);
    double*   part_a1 = (double*)(ws + OFF_A1);
    int*      flags   = (int*)(ws + OFF_FLAG);

    fused_blur<<<NIMG * 64, 256, 0, stream>>>(gt, packed);
    mega2<<<NBLIND + A0BLK, BTHR, 0, stream>>>(packed, packed2, flags,
                                               (const float4*)pred, (const float4*)gt, part_a0);
    skel_fix<<<NIMG, 1024, 0, stream>>>(packed2, flags);
    a1_reduce<<<RBLK, 256, 0, stream>>>((const float4*)pred, (const float4*)gt, packed2, part_a1);
    finalize_kernel<<<1, 256, 0, stream>>>(part_a0, part_a1, (float*)d_out);
}